// Round 14
// baseline (142.289 us; speedup 1.0000x reference)
//
#include <hip/hip_runtime.h>
#include <cstddef>

// ---------------- problem constants ----------------
// N = 100000 nodes, E = 1600000 edges, D = H = 64. fp32 in/out.
// out = relu(GC2(relu(GC1(x))))  with  GC(h) = agg(h) @ Wrel^T + b + h @ Wroot^T
// agg(h)[i] = sum_{e: dst[e]==i} ew[e] * h[src[e]]
//
// 7-dispatch pipeline (round-13 prefetch reverted -- neutral; prep folded into
// the scatter dispatch as extra blocks so it overlaps scatter's latency-bound
// execution on otherwise-idle CUs):
//   memsetAsync : zero gcur (784 B)
//   k_fused     : blocks [0,SB) scatter (block-local dtype detect);
//                 blocks [SB,SB+32) weight frag-pack; rest toBf16
//   k_csrSortC  : per-bucket LDS counting sort -> per-node CSR
//   k_aggB16 x2 : wave per 2 nodes, uniform masked 4-chain gather loop (r11)
//   k_denseM x2 : zero-LDS MFMA 16x16x32 bf16, pre-packed weights

#define FDIM 64
#define BSHC 9                 // 512 nodes per coarse bucket
#define BNC (1 << BSHC)
#define CAPC 8960              // mean 8192 + ~8.5 sigma

static inline size_t align256(size_t x) { return (x + 255) & ~size_t(255); }

typedef __attribute__((ext_vector_type(8))) short bf16x8;
typedef __attribute__((ext_vector_type(4))) float f32x4;

__device__ __forceinline__ ushort f2bf(float f) {   // RNE fp32 -> bf16
    unsigned u = __float_as_uint(f);
    unsigned r = u + 0x7fffu + ((u >> 16) & 1u);
    return (ushort)(r >> 16);
}
__device__ __forceinline__ float bflo(unsigned g) { return __uint_as_float(g << 16); }
__device__ __forceinline__ float bfhi(unsigned g) { return __uint_as_float(g & 0xffff0000u); }
__device__ __forceinline__ unsigned packbf(float lo, float hi) {
    return (unsigned)f2bf(lo) | ((unsigned)f2bf(hi) << 16);
}

// ---------------- fused: scatter + packW + toBf16 in one dispatch ------------
// Blocks [0,sb): coarse ranked scatter, 4096 edges each, block-LOCAL dtype
//   detect (8 KB broadcast reads, deterministic across blocks -> no flag dep).
// Blocks [sb, sb+32): weight fragment pack (16384 items).
// Blocks [sb+32, ...): fp32 -> bf16 feature table, grid-stride.
__global__ void __launch_bounds__(512)
k_fused(const int* __restrict__ ei, const float* __restrict__ ew, int E,
        int* __restrict__ gcur, uint2* __restrict__ recs, int nbc, int sb,
        const float* __restrict__ x, ushort* __restrict__ xb, int nflt,
        const float* __restrict__ wrel1, const float* __restrict__ wroot1,
        const float* __restrict__ wrel2, const float* __restrict__ wroot2,
        ushort* __restrict__ wp1, ushort* __restrict__ wp2, int nbf) {
    int t = threadIdx.x, bid = blockIdx.x;

    if (bid >= sb + 32) {               // ---- toBf16 ----
        int stride = nbf * 512;
        int nq = nflt >> 2;
        for (int iq = (bid - sb - 32) * 512 + t; iq < nq; iq += stride) {
            int i = iq * 4;
            float4 v = *reinterpret_cast<const float4*>(x + i);
            ushort4 o;
            o.x = f2bf(v.x); o.y = f2bf(v.y); o.z = f2bf(v.z); o.w = f2bf(v.w);
            *reinterpret_cast<ushort4*>(xb + i) = o;
        }
        return;
    }
    if (bid >= sb) {                    // ---- packW ----
        // wp[(kk*4+og)*64 + l] lane l holds B[k=kk*32+(l>>4)*8+j][o=og*16+(l&15)]
        int tid = (bid - sb) * 512 + t;           // [0, 16384)
        int layer = tid >> 13;
        int idx = tid & 8191;
        int j = idx & 7, l = (idx >> 3) & 63, og = (idx >> 9) & 3, kk = idx >> 11;
        int k = kk * 32 + ((l >> 4) << 3) + j;
        int o = og * 16 + (l & 15);
        const float* rel  = layer ? wrel2 : wrel1;
        const float* root = layer ? wroot2 : wroot1;
        float v = (k < 64) ? rel[o * FDIM + k] : root[o * FDIM + (k - 64)];
        (layer ? wp2 : wp1)[idx] = f2bf(v);
        return;
    }

    // ---- scatter ----
    __shared__ int any;
    __shared__ int hcnt[256];
    __shared__ int hbase[256];
    if (t == 0) any = 0;
    if (t < 256) hcnt[t] = 0;
    __syncthreads();
    for (int k = t; k < 2048; k += 512)
        if (ei[2 * k + 1] != 0) any = 1;
    __syncthreads();
    int sh = (any == 0) ? 1 : 0;        // 1 => int64 layout (low word at 2i)

    int base = bid * 4096;
    int bkt[8];
    uint2 rec[8];
#pragma unroll
    for (int j = 0; j < 8; ++j) {
        int e = base + j * 512 + t;
        bkt[j] = -1;
        if (e < E) {
            int s = ei[(size_t)e << sh];
            int d = ei[(size_t)(E + e) << sh];
            bkt[j] = d >> BSHC;
            rec[j].x = (unsigned)s | ((unsigned)(d & (BNC - 1)) << 17);
            rec[j].y = __float_as_uint(ew[e]);
            atomicAdd(&hcnt[bkt[j]], 1);
        }
    }
    __syncthreads();
    if (t < nbc) {
        int c = hcnt[t];
        hbase[t] = c ? (t * CAPC + atomicAdd(&gcur[t], c)) : 0;
    }
    __syncthreads();
    if (t < 256) hcnt[t] = 0;           // reuse as local cursor
    __syncthreads();
#pragma unroll
    for (int j = 0; j < 8; ++j) {
        if (bkt[j] >= 0) {
            int r = atomicAdd(&hcnt[bkt[j]], 1);
            int pos = hbase[bkt[j]] + r;
            if (pos < (bkt[j] + 1) * CAPC) recs[pos] = rec[j];  // overflow guard
        }
    }
}

// ---------------- per-coarse-bucket counting sort (512 thr) ----------
__global__ void __launch_bounds__(512)
k_csrSortC(const int* __restrict__ gcur, uint2* __restrict__ recs, int n,
           int* __restrict__ rs, int* __restrict__ re) {
    __shared__ uint2 lrec[CAPC];        // 70 KB
    __shared__ int lh[BNC];
    __shared__ int lo[BNC];
    __shared__ int lcur[BNC];
    int b = blockIdx.x, t = threadIdx.x;
    int base = b * CAPC;
    int cnt = gcur[b];
    if (cnt > CAPC) cnt = CAPC;

    for (int i = t; i < cnt; i += 512) lrec[i] = recs[base + i];
    lh[t] = 0;
    __syncthreads();
    for (int i = t; i < cnt; i += 512) atomicAdd(&lh[lrec[i].x >> 17], 1);
    __syncthreads();
    lo[t] = lh[t];
    __syncthreads();
    for (int off = 1; off < BNC; off <<= 1) {          // inclusive scan, 512 wide
        int v = (t >= off) ? lo[t - off] : 0;
        __syncthreads();
        lo[t] += v;
        __syncthreads();
    }
    {
        int ex = lo[t] - lh[t];
        lcur[t] = ex;
        int node = (b << BSHC) + t;
        if (node < n) { rs[node] = base + ex; re[node] = base + ex + lh[t]; }
    }
    __syncthreads();
    for (int i = t; i < cnt; i += 512) {
        uint2 r = lrec[i];
        int pos = atomicAdd(&lcur[r.x >> 17], 1);
        recs[base + pos] = make_uint2(r.x & 0x1FFFF, r.y);  // .x = src only
    }
}

// ---------------- aggregation: wave per 2 nodes, uniform masked loop ---------
// lane = (q, sl): q = edge slot (lane>>3), sl = feature octet (lane&7).
// Every iteration issues 4 rec loads + 4 b128 gathers (4 independent chains);
// invalid slots: weight 0 (exact-zero contribution; all workspace bf16
// patterns are finite), row masked to 17 bits.
__global__ void __launch_bounds__(256)
k_aggB16(const ushort* __restrict__ hb, const int* __restrict__ rs,
         const int* __restrict__ re, const uint2* __restrict__ recs,
         int n, ushort* __restrict__ aggb) {
    int wavid = (blockIdx.x * blockDim.x + threadIdx.x) >> 6;
    int lane = threadIdx.x & 63;
    int nA = wavid << 1;
    if (nA >= n) return;
    int nB = nA + 1;                    // N even => nB < n always when nA < n
    int q = lane >> 3, sl = lane & 7;
    const uint4* hw4 = reinterpret_cast<const uint4*>(hb);
    int pA = rs[nA], eA = re[nA];
    int pB = rs[nB], eB = re[nB];

    float A0 = 0.f, A1 = 0.f, A2 = 0.f, A3 = 0.f, A4 = 0.f, A5 = 0.f, A6 = 0.f, A7 = 0.f;
    float B0 = 0.f, B1 = 0.f, B2 = 0.f, B3 = 0.f, B4 = 0.f, B5 = 0.f, B6 = 0.f, B7 = 0.f;

#define FMA8(P, g, wf)                                       \
    do {                                                     \
        float w_ = (wf);                                     \
        P##0 = fmaf(bflo((g).x), w_, P##0);                  \
        P##1 = fmaf(bfhi((g).x), w_, P##1);                  \
        P##2 = fmaf(bflo((g).y), w_, P##2);                  \
        P##3 = fmaf(bfhi((g).y), w_, P##3);                  \
        P##4 = fmaf(bflo((g).z), w_, P##4);                  \
        P##5 = fmaf(bfhi((g).z), w_, P##5);                  \
        P##6 = fmaf(bflo((g).w), w_, P##6);                  \
        P##7 = fmaf(bfhi((g).w), w_, P##7);                  \
    } while (0)

    while (pA < eA || pB < eB) {
        int iA0 = pA + q, iA1 = pA + 8 + q;
        int iB0 = pB + q, iB1 = pB + 8 + q;
        uint2 ra0 = recs[iA0];
        uint2 ra1 = recs[iA1];
        uint2 rb0 = recs[iB0];
        uint2 rb1 = recs[iB1];
        uint4 ga0 = hw4[(size_t)(ra0.x & 0x1FFFFu) * 8 + sl];
        uint4 ga1 = hw4[(size_t)(ra1.x & 0x1FFFFu) * 8 + sl];
        uint4 gb0 = hw4[(size_t)(rb0.x & 0x1FFFFu) * 8 + sl];
        uint4 gb1 = hw4[(size_t)(rb1.x & 0x1FFFFu) * 8 + sl];
        float wa0 = (iA0 < eA) ? __uint_as_float(ra0.y) : 0.f;
        float wa1 = (iA1 < eA) ? __uint_as_float(ra1.y) : 0.f;
        float wb0 = (iB0 < eB) ? __uint_as_float(rb0.y) : 0.f;
        float wb1 = (iB1 < eB) ? __uint_as_float(rb1.y) : 0.f;
        FMA8(A, ga0, wa0);
        FMA8(A, ga1, wa1);
        FMA8(B, gb0, wb0);
        FMA8(B, gb1, wb1);
        pA = (pA + 16 < eA) ? pA + 16 : eA;
        pB = (pB + 16 < eB) ? pB + 16 : eB;
    }
#undef FMA8

#define RED2(d)                                                  \
    A0 += __shfl_xor(A0, d, 64); A1 += __shfl_xor(A1, d, 64);    \
    A2 += __shfl_xor(A2, d, 64); A3 += __shfl_xor(A3, d, 64);    \
    A4 += __shfl_xor(A4, d, 64); A5 += __shfl_xor(A5, d, 64);    \
    A6 += __shfl_xor(A6, d, 64); A7 += __shfl_xor(A7, d, 64);    \
    B0 += __shfl_xor(B0, d, 64); B1 += __shfl_xor(B1, d, 64);    \
    B2 += __shfl_xor(B2, d, 64); B3 += __shfl_xor(B3, d, 64);    \
    B4 += __shfl_xor(B4, d, 64); B5 += __shfl_xor(B5, d, 64);    \
    B6 += __shfl_xor(B6, d, 64); B7 += __shfl_xor(B7, d, 64);
    RED2(8) RED2(16) RED2(32)
#undef RED2

    if (q == 0) {                       // lanes 0..7 write node A
        uint4 o;
        o.x = packbf(A0, A1);
        o.y = packbf(A2, A3);
        o.z = packbf(A4, A5);
        o.w = packbf(A6, A7);
        reinterpret_cast<uint4*>(aggb + (size_t)nA * FDIM)[sl] = o;
    } else if (q == 1) {                // lanes 8..15 write node B
        uint4 o;
        o.x = packbf(B0, B1);
        o.y = packbf(B2, B3);
        o.z = packbf(B4, B5);
        o.w = packbf(B6, B7);
        reinterpret_cast<uint4*>(aggb + (size_t)nB * FDIM)[sl] = o;
    }
}

// ---------------- dense via MFMA: out = relu([agg|root] @ B + bias) ----------
// Wave = 16 nodes x 64 outs. A-frag: row=l&15, k=(l>>4)*8+j (16B/lane loads).
// B from pre-packed wp (contiguous per fragment). C/D: col=l&15, row=(l>>4)*4+r.
template<int OUTBF>
__global__ void __launch_bounds__(256)
k_denseM(const ushort* __restrict__ aggb, const ushort* __restrict__ rootb,
         const ushort* __restrict__ wp, const float* __restrict__ bias,
         float* __restrict__ outp, ushort* __restrict__ outb, int n) {
    int t = threadIdx.x;
    int wv = t >> 6, l = t & 63;
    int n0 = blockIdx.x * 64 + wv * 16;
    int row = l & 15, half = l >> 4;

    int node = n0 + row;
    bool inb = node < n;
    const ushort* ap = aggb + (size_t)node * FDIM + half * 8;
    const ushort* rp = rootb + (size_t)node * FDIM + half * 8;
    bf16x8 a0 = inb ? *reinterpret_cast<const bf16x8*>(ap)      : bf16x8{0,0,0,0,0,0,0,0};
    bf16x8 a1 = inb ? *reinterpret_cast<const bf16x8*>(ap + 32) : bf16x8{0,0,0,0,0,0,0,0};
    bf16x8 a2 = inb ? *reinterpret_cast<const bf16x8*>(rp)      : bf16x8{0,0,0,0,0,0,0,0};
    bf16x8 a3 = inb ? *reinterpret_cast<const bf16x8*>(rp + 32) : bf16x8{0,0,0,0,0,0,0,0};

    f32x4 acc[4];
#pragma unroll
    for (int og = 0; og < 4; ++og) acc[og] = f32x4{0.f, 0.f, 0.f, 0.f};

#pragma unroll
    for (int og = 0; og < 4; ++og) {
        const bf16x8* wb = reinterpret_cast<const bf16x8*>(wp) + og * 64 + l;
        acc[og] = __builtin_amdgcn_mfma_f32_16x16x32_bf16(a0, wb[0],       acc[og], 0, 0, 0);
        acc[og] = __builtin_amdgcn_mfma_f32_16x16x32_bf16(a1, wb[4 * 64],  acc[og], 0, 0, 0);
        acc[og] = __builtin_amdgcn_mfma_f32_16x16x32_bf16(a2, wb[8 * 64],  acc[og], 0, 0, 0);
        acc[og] = __builtin_amdgcn_mfma_f32_16x16x32_bf16(a3, wb[12 * 64], acc[og], 0, 0, 0);
    }

    int rbase = n0 + half * 4;
#pragma unroll
    for (int og = 0; og < 4; ++og) {
        float bb = bias[og * 16 + row];
#pragma unroll
        for (int r = 0; r < 4; ++r) {
            int nd = rbase + r;
            if (nd < n) {
                float v = fmaxf(acc[og][r] + bb, 0.f);
                if (OUTBF) outb[(size_t)nd * FDIM + og * 16 + row] = f2bf(v);
                else       outp[(size_t)nd * FDIM + og * 16 + row] = v;
            }
        }
    }
}

// ---------------- launch ----------------
extern "C" void kernel_launch(void* const* d_in, const int* in_sizes, int n_in,
                              void* d_out, int out_size, void* d_ws, size_t ws_size,
                              hipStream_t stream) {
    const float* x      = (const float*)d_in[0];
    const int*   ei     = (const int*)d_in[1];
    const float* ew     = (const float*)d_in[2];
    const float* w1rel  = (const float*)d_in[3];
    const float* b1     = (const float*)d_in[4];
    const float* w1root = (const float*)d_in[5];
    const float* w2rel  = (const float*)d_in[6];
    const float* b2     = (const float*)d_in[7];
    const float* w2root = (const float*)d_in[8];
    float* out = (float*)d_out;

    int N = in_sizes[0] / FDIM;
    int E = in_sizes[2];
    int NBC = (N + BNC - 1) >> BSHC;   // 196 coarse buckets
    int SB  = (E + 4095) / 4096;       // 391 scatter blocks
    int NBF = 782;                     // toBf16 blocks

    // workspace: recs 14.1MB (+64-rec pad) + xb/h1b/aggb 12.8MB each + misc
    char* w = (char*)d_ws;
    int* gcur    = (int*)w;    w += align256((size_t)NBC * 4);
    int* rs      = (int*)w;    w += align256((size_t)N * 4);
    int* re      = (int*)w;    w += align256((size_t)N * 4);
    ushort* wp1  = (ushort*)w; w += align256(8192 * 2);
    ushort* wp2  = (ushort*)w; w += align256(8192 * 2);
    uint2* recs  = (uint2*)w;  w += align256(((size_t)NBC * CAPC + 64) * 8);
    ushort* aggb = (ushort*)w; w += align256((size_t)N * FDIM * 2);
    ushort* xb   = (ushort*)w; w += align256((size_t)N * FDIM * 2);
    ushort* h1b  = (ushort*)w; w += align256((size_t)N * FDIM * 2);

    int nflt = N * FDIM;
    hipMemsetAsync(gcur, 0, (size_t)NBC * sizeof(int), stream);
    k_fused<<<SB + 32 + NBF, 512, 0, stream>>>(
        ei, ew, E, gcur, recs, NBC, SB, x, xb, nflt,
        w1rel, w1root, w2rel, w2root, wp1, wp2, NBF);
    k_csrSortC<<<NBC, 512, 0, stream>>>(gcur, recs, N, rs, re);

    // layer 1: gather bf16(x); root = bf16(x); emit h1 bf16
    k_aggB16<<<(N + 7) / 8, 256, 0, stream>>>(xb, rs, re, recs, N, aggb);
    k_denseM<1><<<(N + 63) / 64, 256, 0, stream>>>(aggb, xb, wp1, b1, nullptr, h1b, N);
    // layer 2: gather bf16(h1); root = h1 bf16; emit fp32 out
    k_aggB16<<<(N + 7) / 8, 256, 0, stream>>>(h1b, rs, re, recs, N, aggb);
    k_denseM<0><<<(N + 63) / 64, 256, 0, stream>>>(aggb, h1b, wp2, b2, out, nullptr, N);
}

// Round 15
// 140.376 us; speedup vs baseline: 1.0136x; 1.0136x over previous
//
#include <hip/hip_runtime.h>
#include <cstddef>

// ---------------- problem constants ----------------
// N = 100000 nodes, E = 1600000 edges, D = H = 64. fp32 in/out.
// out = relu(GC2(relu(GC1(x))))  with  GC(h) = agg(h) @ Wrel^T + b + h @ Wroot^T
// agg(h)[i] = sum_{e: dst[e]==i} ew[e] * h[src[e]]
//
// Final configuration (= round-11 best, 140.7 us):
//   k_prep      : bf16 feature table + weight frag-pack + dtype detect + zero
//   k_scatterC  : coarse ranked scatter into 196 buckets of 512 nodes (~1x WA)
//   k_csrSortC  : per-bucket LDS counting sort -> per-node CSR
//   k_aggB16 x2 : wave per 2 nodes, uniform masked 4-chain gather loop
//   k_denseM x2 : zero-LDS MFMA 16x16x32 bf16, pre-packed weights
// Converged: agg is bound by random 128-B row-gather service (~8 TB/s
// request-side); shfl-feed (r12), rec-prefetch (r13), prep-overlap (r14),
// agg+dense fusion (r10) all neutral or negative.

#define FDIM 64
#define BSHC 9                 // 512 nodes per coarse bucket
#define BNC (1 << BSHC)
#define CAPC 8960              // mean 8192 + ~8.5 sigma

static inline size_t align256(size_t x) { return (x + 255) & ~size_t(255); }

typedef __attribute__((ext_vector_type(8))) short bf16x8;
typedef __attribute__((ext_vector_type(4))) float f32x4;

__device__ __forceinline__ ushort f2bf(float f) {   // RNE fp32 -> bf16
    unsigned u = __float_as_uint(f);
    unsigned r = u + 0x7fffu + ((u >> 16) & 1u);
    return (ushort)(r >> 16);
}
__device__ __forceinline__ float bflo(unsigned g) { return __uint_as_float(g << 16); }
__device__ __forceinline__ float bfhi(unsigned g) { return __uint_as_float(g & 0xffff0000u); }
__device__ __forceinline__ unsigned packbf(float lo, float hi) {
    return (unsigned)f2bf(lo) | ((unsigned)f2bf(hi) << 16);
}

// ---------------- prep: toBf16 (all) + detect/zero/pad (blk 0) + packW -------
__global__ void __launch_bounds__(256)
k_prep(const float* __restrict__ x, ushort* __restrict__ xb, int nflt,
       const int* __restrict__ ei, int* __restrict__ flag,
       int* __restrict__ gcur, int nbc, uint2* __restrict__ pad,
       const float* __restrict__ wrel1, const float* __restrict__ wroot1,
       const float* __restrict__ wrel2, const float* __restrict__ wroot2,
       ushort* __restrict__ wp1, ushort* __restrict__ wp2) {
    int t = threadIdx.x, bid = blockIdx.x;
    int i = (bid * 256 + t) * 4;
    if (i < nflt) {
        float4 v = *reinterpret_cast<const float4*>(x + i);
        ushort4 o;
        o.x = f2bf(v.x); o.y = f2bf(v.y); o.z = f2bf(v.z); o.w = f2bf(v.w);
        *reinterpret_cast<ushort4*>(xb + i) = o;
    }
    if (bid == 0) {
        __shared__ int any;
        if (t == 0) any = 0;
        __syncthreads();
        for (int k = t; k < 2048; k += 256)
            if (ei[2 * k + 1] != 0) any = 1;
        for (int j = t; j < nbc; j += 256) gcur[j] = 0;
        if (t < 64) pad[t] = make_uint2(0u, 0u);   // rec-overshoot pad (src 0, w 0)
        __syncthreads();
        if (t == 0) *flag = (any == 0) ? 1 : 0;   // 1 => int64 layout
    } else if (bid <= 64) {
        // wp[(kk*4+og)*64 + l] lane l holds B[k=kk*32+(l>>4)*8+j][o=og*16+(l&15)]
        int tid = (bid - 1) * 256 + t;            // [0, 16384)
        int layer = tid >> 13;
        int idx = tid & 8191;
        int j = idx & 7, l = (idx >> 3) & 63, og = (idx >> 9) & 3, kk = idx >> 11;
        int k = kk * 32 + ((l >> 4) << 3) + j;
        int o = og * 16 + (l & 15);
        const float* rel  = layer ? wrel2 : wrel1;
        const float* root = layer ? wroot2 : wroot1;
        float v = (k < 64) ? rel[o * FDIM + k] : root[o * FDIM + (k - 64)];
        (layer ? wp2 : wp1)[idx] = f2bf(v);
    }
}

// ---------------- pass 1: coarse ranked scatter (196 buckets) ----------------
__global__ void __launch_bounds__(512)
k_scatterC(const int* __restrict__ ei, const float* __restrict__ ew, int E,
           const int* __restrict__ flag, int* __restrict__ gcur,
           uint2* __restrict__ recs, int nbc) {
    __shared__ int hcnt[256];
    __shared__ int hbase[256];
    int t = threadIdx.x;
    int base = blockIdx.x * 4096;
    int sh = *flag;
    if (t < 256) hcnt[t] = 0;
    __syncthreads();

    int bkt[8];
    uint2 rec[8];
#pragma unroll
    for (int j = 0; j < 8; ++j) {
        int e = base + j * 512 + t;
        bkt[j] = -1;
        if (e < E) {
            int s = ei[(size_t)e << sh];
            int d = ei[(size_t)(E + e) << sh];
            bkt[j] = d >> BSHC;
            rec[j].x = (unsigned)s | ((unsigned)(d & (BNC - 1)) << 17);
            rec[j].y = __float_as_uint(ew[e]);
            atomicAdd(&hcnt[bkt[j]], 1);
        }
    }
    __syncthreads();
    if (t < nbc) {
        int c = hcnt[t];
        hbase[t] = c ? (t * CAPC + atomicAdd(&gcur[t], c)) : 0;
    }
    __syncthreads();
    if (t < 256) hcnt[t] = 0;          // reuse as local cursor
    __syncthreads();
#pragma unroll
    for (int j = 0; j < 8; ++j) {
        if (bkt[j] >= 0) {
            int r = atomicAdd(&hcnt[bkt[j]], 1);
            int pos = hbase[bkt[j]] + r;
            if (pos < (bkt[j] + 1) * CAPC) recs[pos] = rec[j];  // overflow guard
        }
    }
}

// ---------------- pass 2: per-coarse-bucket counting sort (512 thr) ----------
__global__ void __launch_bounds__(512)
k_csrSortC(const int* __restrict__ gcur, uint2* __restrict__ recs, int n,
           int* __restrict__ rs, int* __restrict__ re) {
    __shared__ uint2 lrec[CAPC];        // 70 KB
    __shared__ int lh[BNC];
    __shared__ int lo[BNC];
    __shared__ int lcur[BNC];
    int b = blockIdx.x, t = threadIdx.x;
    int base = b * CAPC;
    int cnt = gcur[b];
    if (cnt > CAPC) cnt = CAPC;

    for (int i = t; i < cnt; i += 512) lrec[i] = recs[base + i];
    lh[t] = 0;
    __syncthreads();
    for (int i = t; i < cnt; i += 512) atomicAdd(&lh[lrec[i].x >> 17], 1);
    __syncthreads();
    lo[t] = lh[t];
    __syncthreads();
    for (int off = 1; off < BNC; off <<= 1) {          // inclusive scan, 512 wide
        int v = (t >= off) ? lo[t - off] : 0;
        __syncthreads();
        lo[t] += v;
        __syncthreads();
    }
    {
        int ex = lo[t] - lh[t];
        lcur[t] = ex;
        int node = (b << BSHC) + t;
        if (node < n) { rs[node] = base + ex; re[node] = base + ex + lh[t]; }
    }
    __syncthreads();
    for (int i = t; i < cnt; i += 512) {
        uint2 r = lrec[i];
        int pos = atomicAdd(&lcur[r.x >> 17], 1);
        recs[base + pos] = make_uint2(r.x & 0x1FFFF, r.y);  // .x = src only
    }
}

// ---------------- aggregation: wave per 2 nodes, uniform masked loop ---------
// lane = (q, sl): q = edge slot (lane>>3), sl = feature octet (lane&7).
// Every iteration issues 4 rec loads + 4 b128 gathers (4 independent chains);
// invalid slots: weight 0, row masked to 17 bits. Overshoot reads land in
// valid recs or the zeroed 64-rec pad, contributing exact x0.
__global__ void __launch_bounds__(256)
k_aggB16(const ushort* __restrict__ hb, const int* __restrict__ rs,
         const int* __restrict__ re, const uint2* __restrict__ recs,
         int n, ushort* __restrict__ aggb) {
    int wavid = (blockIdx.x * blockDim.x + threadIdx.x) >> 6;
    int lane = threadIdx.x & 63;
    int nA = wavid << 1;
    if (nA >= n) return;
    int nB = nA + 1;                    // N even => nB < n always when nA < n
    int q = lane >> 3, sl = lane & 7;
    const uint4* hw4 = reinterpret_cast<const uint4*>(hb);
    int pA = rs[nA], eA = re[nA];
    int pB = rs[nB], eB = re[nB];

    float A0 = 0.f, A1 = 0.f, A2 = 0.f, A3 = 0.f, A4 = 0.f, A5 = 0.f, A6 = 0.f, A7 = 0.f;
    float B0 = 0.f, B1 = 0.f, B2 = 0.f, B3 = 0.f, B4 = 0.f, B5 = 0.f, B6 = 0.f, B7 = 0.f;

#define FMA8(P, g, wf)                                       \
    do {                                                     \
        float w_ = (wf);                                     \
        P##0 = fmaf(bflo((g).x), w_, P##0);                  \
        P##1 = fmaf(bfhi((g).x), w_, P##1);                  \
        P##2 = fmaf(bflo((g).y), w_, P##2);                  \
        P##3 = fmaf(bfhi((g).y), w_, P##3);                  \
        P##4 = fmaf(bflo((g).z), w_, P##4);                  \
        P##5 = fmaf(bfhi((g).z), w_, P##5);                  \
        P##6 = fmaf(bflo((g).w), w_, P##6);                  \
        P##7 = fmaf(bfhi((g).w), w_, P##7);                  \
    } while (0)

    while (pA < eA || pB < eB) {
        int iA0 = pA + q, iA1 = pA + 8 + q;
        int iB0 = pB + q, iB1 = pB + 8 + q;
        uint2 ra0 = recs[iA0];
        uint2 ra1 = recs[iA1];
        uint2 rb0 = recs[iB0];
        uint2 rb1 = recs[iB1];
        uint4 ga0 = hw4[(size_t)(ra0.x & 0x1FFFFu) * 8 + sl];
        uint4 ga1 = hw4[(size_t)(ra1.x & 0x1FFFFu) * 8 + sl];
        uint4 gb0 = hw4[(size_t)(rb0.x & 0x1FFFFu) * 8 + sl];
        uint4 gb1 = hw4[(size_t)(rb1.x & 0x1FFFFu) * 8 + sl];
        float wa0 = (iA0 < eA) ? __uint_as_float(ra0.y) : 0.f;
        float wa1 = (iA1 < eA) ? __uint_as_float(ra1.y) : 0.f;
        float wb0 = (iB0 < eB) ? __uint_as_float(rb0.y) : 0.f;
        float wb1 = (iB1 < eB) ? __uint_as_float(rb1.y) : 0.f;
        FMA8(A, ga0, wa0);
        FMA8(A, ga1, wa1);
        FMA8(B, gb0, wb0);
        FMA8(B, gb1, wb1);
        pA = (pA + 16 < eA) ? pA + 16 : eA;
        pB = (pB + 16 < eB) ? pB + 16 : eB;
    }
#undef FMA8

#define RED2(d)                                                  \
    A0 += __shfl_xor(A0, d, 64); A1 += __shfl_xor(A1, d, 64);    \
    A2 += __shfl_xor(A2, d, 64); A3 += __shfl_xor(A3, d, 64);    \
    A4 += __shfl_xor(A4, d, 64); A5 += __shfl_xor(A5, d, 64);    \
    A6 += __shfl_xor(A6, d, 64); A7 += __shfl_xor(A7, d, 64);    \
    B0 += __shfl_xor(B0, d, 64); B1 += __shfl_xor(B1, d, 64);    \
    B2 += __shfl_xor(B2, d, 64); B3 += __shfl_xor(B3, d, 64);    \
    B4 += __shfl_xor(B4, d, 64); B5 += __shfl_xor(B5, d, 64);    \
    B6 += __shfl_xor(B6, d, 64); B7 += __shfl_xor(B7, d, 64);
    RED2(8) RED2(16) RED2(32)
#undef RED2

    if (q == 0) {                       // lanes 0..7 write node A
        uint4 o;
        o.x = packbf(A0, A1);
        o.y = packbf(A2, A3);
        o.z = packbf(A4, A5);
        o.w = packbf(A6, A7);
        reinterpret_cast<uint4*>(aggb + (size_t)nA * FDIM)[sl] = o;
    } else if (q == 1) {                // lanes 8..15 write node B
        uint4 o;
        o.x = packbf(B0, B1);
        o.y = packbf(B2, B3);
        o.z = packbf(B4, B5);
        o.w = packbf(B6, B7);
        reinterpret_cast<uint4*>(aggb + (size_t)nB * FDIM)[sl] = o;
    }
}

// ---------------- dense via MFMA: out = relu([agg|root] @ B + bias) ----------
// Wave = 16 nodes x 64 outs. A-frag: row=l&15, k=(l>>4)*8+j (16B/lane loads).
// B from pre-packed wp (contiguous per fragment). C/D: col=l&15, row=(l>>4)*4+r.
template<int OUTBF>
__global__ void __launch_bounds__(256)
k_denseM(const ushort* __restrict__ aggb, const ushort* __restrict__ rootb,
         const ushort* __restrict__ wp, const float* __restrict__ bias,
         float* __restrict__ outp, ushort* __restrict__ outb, int n) {
    int t = threadIdx.x;
    int wv = t >> 6, l = t & 63;
    int n0 = blockIdx.x * 64 + wv * 16;
    int row = l & 15, half = l >> 4;

    int node = n0 + row;
    bool inb = node < n;
    const ushort* ap = aggb + (size_t)node * FDIM + half * 8;
    const ushort* rp = rootb + (size_t)node * FDIM + half * 8;
    bf16x8 a0 = inb ? *reinterpret_cast<const bf16x8*>(ap)      : bf16x8{0,0,0,0,0,0,0,0};
    bf16x8 a1 = inb ? *reinterpret_cast<const bf16x8*>(ap + 32) : bf16x8{0,0,0,0,0,0,0,0};
    bf16x8 a2 = inb ? *reinterpret_cast<const bf16x8*>(rp)      : bf16x8{0,0,0,0,0,0,0,0};
    bf16x8 a3 = inb ? *reinterpret_cast<const bf16x8*>(rp + 32) : bf16x8{0,0,0,0,0,0,0,0};

    f32x4 acc[4];
#pragma unroll
    for (int og = 0; og < 4; ++og) acc[og] = f32x4{0.f, 0.f, 0.f, 0.f};

#pragma unroll
    for (int og = 0; og < 4; ++og) {
        const bf16x8* wb = reinterpret_cast<const bf16x8*>(wp) + og * 64 + l;
        acc[og] = __builtin_amdgcn_mfma_f32_16x16x32_bf16(a0, wb[0],       acc[og], 0, 0, 0);
        acc[og] = __builtin_amdgcn_mfma_f32_16x16x32_bf16(a1, wb[4 * 64],  acc[og], 0, 0, 0);
        acc[og] = __builtin_amdgcn_mfma_f32_16x16x32_bf16(a2, wb[8 * 64],  acc[og], 0, 0, 0);
        acc[og] = __builtin_amdgcn_mfma_f32_16x16x32_bf16(a3, wb[12 * 64], acc[og], 0, 0, 0);
    }

    int rbase = n0 + half * 4;
#pragma unroll
    for (int og = 0; og < 4; ++og) {
        float bb = bias[og * 16 + row];
#pragma unroll
        for (int r = 0; r < 4; ++r) {
            int nd = rbase + r;
            if (nd < n) {
                float v = fmaxf(acc[og][r] + bb, 0.f);
                if (OUTBF) outb[(size_t)nd * FDIM + og * 16 + row] = f2bf(v);
                else       outp[(size_t)nd * FDIM + og * 16 + row] = v;
            }
        }
    }
}

// ---------------- launch ----------------
extern "C" void kernel_launch(void* const* d_in, const int* in_sizes, int n_in,
                              void* d_out, int out_size, void* d_ws, size_t ws_size,
                              hipStream_t stream) {
    const float* x      = (const float*)d_in[0];
    const int*   ei     = (const int*)d_in[1];
    const float* ew     = (const float*)d_in[2];
    const float* w1rel  = (const float*)d_in[3];
    const float* b1     = (const float*)d_in[4];
    const float* w1root = (const float*)d_in[5];
    const float* w2rel  = (const float*)d_in[6];
    const float* b2     = (const float*)d_in[7];
    const float* w2root = (const float*)d_in[8];
    float* out = (float*)d_out;

    int N = in_sizes[0] / FDIM;
    int E = in_sizes[2];
    int NBC = (N + BNC - 1) >> BSHC;   // 196 coarse buckets

    // workspace: recs 14.1MB (+64-rec pad) + xb/h1b/aggb 12.8MB each + misc
    char* w = (char*)d_ws;
    int* flag    = (int*)w;    w += align256(256);
    int* gcur    = (int*)w;    w += align256((size_t)NBC * 4);
    int* rs      = (int*)w;    w += align256((size_t)N * 4);
    int* re      = (int*)w;    w += align256((size_t)N * 4);
    ushort* wp1  = (ushort*)w; w += align256(8192 * 2);
    ushort* wp2  = (ushort*)w; w += align256(8192 * 2);
    uint2* recs  = (uint2*)w;  w += align256(((size_t)NBC * CAPC + 64) * 8);
    ushort* aggb = (ushort*)w; w += align256((size_t)N * FDIM * 2);
    ushort* xb   = (ushort*)w; w += align256((size_t)N * FDIM * 2);
    ushort* h1b  = (ushort*)w; w += align256((size_t)N * FDIM * 2);

    int nflt = N * FDIM;
    k_prep<<<(nflt / 4 + 255) / 256, 256, 0, stream>>>(
        x, xb, nflt, ei, flag, gcur, NBC, recs + (size_t)NBC * CAPC,
        w1rel, w1root, w2rel, w2root, wp1, wp2);
    k_scatterC<<<(E + 4095) / 4096, 512, 0, stream>>>(ei, ew, E, flag, gcur, recs, NBC);
    k_csrSortC<<<NBC, 512, 0, stream>>>(gcur, recs, N, rs, re);

    // layer 1: gather bf16(x); root = bf16(x); emit h1 bf16
    k_aggB16<<<(N + 7) / 8, 256, 0, stream>>>(xb, rs, re, recs, N, aggb);
    k_denseM<1><<<(N + 63) / 64, 256, 0, stream>>>(aggb, xb, wp1, b1, nullptr, h1b, N);
    // layer 2: gather bf16(h1); root = h1 bf16; emit fp32 out
    k_aggB16<<<(N + 7) / 8, 256, 0, stream>>>(h1b, rs, re, recs, N, aggb);
    k_denseM<0><<<(N + 63) / 64, 256, 0, stream>>>(aggb, h1b, wp2, b2, out, nullptr, N);
}